// Round 1
// baseline (328.958 us; speedup 1.0000x reference)
//
#include <hip/hip_runtime.h>
#include <hip/hip_bf16.h>
#include <stdint.h>

typedef __bf16 bf16;
typedef __bf16 bf16x4 __attribute__((ext_vector_type(4)));
typedef __bf16 bf16x8 __attribute__((ext_vector_type(8)));
typedef float f32x4 __attribute__((ext_vector_type(4)));

// Problem dims
#define BB   2048
#define ISZ  512
#define NN   2048
#define OSZ  128

// ---------------------------------------------------------------------------
// pack: fp32 [M][W] -> bf16 dst[m][col_off + w] (row stride ld), 4 elems/thread
// ---------------------------------------------------------------------------
__global__ void pack_bf16_k(const float* __restrict__ src, bf16* __restrict__ dst,
                            int W, int ld, int col_off, int total4) {
  int idx = blockIdx.x * blockDim.x + threadIdx.x;
  if (idx >= total4) return;
  int e = idx * 4;
  int m = e / W;
  int c = e - m * W;
  const float4 v = *reinterpret_cast<const float4*>(src + e);
  bf16x4 o;
  o[0] = (bf16)v.x; o[1] = (bf16)v.y; o[2] = (bf16)v.z; o[3] = (bf16)v.w;
  *reinterpret_cast<bf16x4*>(dst + (size_t)m * ld + col_off + c) = o;
}

// ---------------------------------------------------------------------------
// transpose fp32 [K][Ncols] -> bf16 dst[n][k_off + k] (row stride ld_dst)
// MODE 0: plain   MODE 1: zero diagonal (k==n)   MODE 2: multiply by mask
// ---------------------------------------------------------------------------
template<int MODE>
__global__ void transpose_bf16_k(const float* __restrict__ src, const float* __restrict__ msk,
                                 int Ncols, bf16* __restrict__ dst, int ld_dst, int k_off) {
  __shared__ float t[32][33];
  const int k0 = blockIdx.x * 32, n0 = blockIdx.y * 32;
  const int tx = threadIdx.x, ty = threadIdx.y;
#pragma unroll
  for (int i = 0; i < 4; ++i) {
    int k = k0 + ty + i * 8;
    float v = src[(size_t)k * Ncols + n0 + tx];
    if (MODE == 1 && k == (n0 + tx)) v = 0.f;
    if (MODE == 2) v *= msk[(size_t)k * Ncols + n0 + tx];
    t[ty + i * 8][tx] = v;
  }
  __syncthreads();
#pragma unroll
  for (int i = 0; i < 4; ++i) {
    int n = n0 + ty + i * 8;
    dst[(size_t)n * ld_dst + k_off + k0 + tx] = (bf16)t[tx][ty + i * 8];
  }
}

// ---------------------------------------------------------------------------
// GEMM: C[M][N] = A[M][K] (bf16, row-major) * Bt[N][K]^T (bf16, B^T layout)
// EPI 0: h = hin*0.9 + relu(acc + bias[n])*0.1 ; write fp32 out + bf16 nxt
// EPI 1: write fp32 acc
// m97 structure: BK=32, 256 threads (4 waves, 2x2), global_load_lds width 16.
// ---------------------------------------------------------------------------
__device__ __forceinline__ void gload16(const bf16* g, bf16* l) {
  __builtin_amdgcn_global_load_lds(
      (const __attribute__((address_space(1))) void*)g,
      (__attribute__((address_space(3))) void*)l, 16, 0, 0);
}

template<int BM, int BN, int EPI>
__global__ __launch_bounds__(256)
void gemm_bf16_k(const bf16* __restrict__ A, const bf16* __restrict__ Bt,
                 int K, int lda, int ldb,
                 const float* __restrict__ hin, const float* __restrict__ bias,
                 float* __restrict__ outf, int ld_out,
                 bf16* __restrict__ nxt, int ld_nxt) {
  constexpr int BK = 32;
  constexpr int WM = BM / 2, WN = BN / 2;
  constexpr int FM = WM / 16, FN = WN / 16;
  __shared__ bf16 As[BM][BK];
  __shared__ bf16 Bs[BN][BK];
  const int tid  = threadIdx.x;
  const int lane = tid & 63;
  const int wave = tid >> 6;
  const int m0 = blockIdx.y * BM, n0 = blockIdx.x * BN;
  const int wm0 = (wave >> 1) * WM, wn0 = (wave & 1) * WN;
  const int lrow = lane >> 2;        // 0..15 row within 16-row staging chunk
  const int lcol = (lane & 3) * 8;   // element col within BK
  const int frow = lane & 15;        // fragment row/col index
  const int fk   = (lane >> 4) * 8;  // fragment k offset

  f32x4 acc[FM][FN];
#pragma unroll
  for (int i = 0; i < FM; ++i)
#pragma unroll
    for (int j = 0; j < FN; ++j)
#pragma unroll
      for (int r = 0; r < 4; ++r) acc[i][j][r] = 0.f;

  for (int k0 = 0; k0 < K; k0 += BK) {
    // stage A tile [BM][BK] and B tile [BN][BK] (each chunk = 16 rows = 1024B)
#pragma unroll
    for (int c = wave; c < BM / 16; c += 4) {
      const bf16* g = A + (size_t)(m0 + c * 16 + lrow) * lda + k0 + lcol;
      gload16(g, &As[0][0] + c * 512);
    }
#pragma unroll
    for (int c = wave; c < BN / 16; c += 4) {
      const bf16* g = Bt + (size_t)(n0 + c * 16 + lrow) * ldb + k0 + lcol;
      gload16(g, &Bs[0][0] + c * 512);
    }
    __syncthreads();

    bf16x8 af[FM], bfr[FN];
#pragma unroll
    for (int i = 0; i < FM; ++i)
      af[i] = *reinterpret_cast<const bf16x8*>(&As[wm0 + i * 16 + frow][fk]);
#pragma unroll
    for (int j = 0; j < FN; ++j)
      bfr[j] = *reinterpret_cast<const bf16x8*>(&Bs[wn0 + j * 16 + frow][fk]);
#pragma unroll
    for (int i = 0; i < FM; ++i)
#pragma unroll
      for (int j = 0; j < FN; ++j)
        acc[i][j] = __builtin_amdgcn_mfma_f32_16x16x32_bf16(af[i], bfr[j], acc[i][j], 0, 0, 0);
    __syncthreads();
  }

  // epilogue: C/D layout col = lane&15, row = (lane>>4)*4 + reg
#pragma unroll
  for (int i = 0; i < FM; ++i) {
#pragma unroll
    for (int j = 0; j < FN; ++j) {
#pragma unroll
      for (int r = 0; r < 4; ++r) {
        int row = m0 + wm0 + i * 16 + (lane >> 4) * 4 + r;
        int col = n0 + wn0 + j * 16 + (lane & 15);
        float v = acc[i][j][r];
        if (EPI == 0) {
          float pre = v + bias[col];
          float h = hin[(size_t)row * ld_out + col] * 0.9f + fmaxf(pre, 0.f) * 0.1f;
          outf[(size_t)row * ld_out + col] = h;
          nxt[(size_t)row * ld_nxt + col] = (bf16)h;
        } else {
          outf[(size_t)row * ld_out + col] = v;
        }
      }
    }
  }
}

// ---------------------------------------------------------------------------
extern "C" void kernel_launch(void* const* d_in, const int* in_sizes, int n_in,
                              void* d_out, int out_size, void* d_ws, size_t ws_size,
                              hipStream_t stream) {
  const float* x        = (const float*)d_in[0];
  const float* h0_in    = (const float*)d_in[1];
  const float* h1_in    = (const float*)d_in[2];
  const float* h2_in    = (const float*)d_in[3];
  const float* i_to_h0  = (const float*)d_in[4];
  const float* h0_w     = (const float*)d_in[5];
  const float* h0_b     = (const float*)d_in[6];
  const float* h0_to_h1 = (const float*)d_in[7];
  const float* h1_w     = (const float*)d_in[8];
  const float* h1_b     = (const float*)d_in[9];
  const float* h1_to_h2 = (const float*)d_in[10];
  const float* h2_w     = (const float*)d_in[11];
  const float* h2_b     = (const float*)d_in[12];
  const float* w_out    = (const float*)d_in[13];
  const float* m01      = (const float*)d_in[14];
  const float* m12      = (const float*)d_in[15];
  float* out = (float*)d_out;

  // workspace layout (bf16 buffers)
  uint8_t* ws = (uint8_t*)d_ws;
  constexpr size_t OFF_A0  = 0;                       // [2048][2560]
  constexpr size_t OFF_W0  = OFF_A0  + 10485760;      // [2048][2560]  (N x K0)
  constexpr size_t OFF_A1  = OFF_W0  + 10485760;      // [2048][4096]
  constexpr size_t OFF_W1  = OFF_A1  + 16777216;      // [2048][4096]
  constexpr size_t OFF_A2  = OFF_W1  + 16777216;      // [2048][4096]
  constexpr size_t OFF_W2  = OFF_A2  + 16777216;      // [2048][4096]
  constexpr size_t OFF_A3  = OFF_W2  + 16777216;      // [2048][2048]
  constexpr size_t OFF_WO  = OFF_A3  + 8388608;       // [128][2048]
  constexpr size_t WS_NEED = OFF_WO  + 524288;        // ~92.5 MB
  if (ws_size < WS_NEED) return;

  bf16* A0  = (bf16*)(ws + OFF_A0);
  bf16* Wt0 = (bf16*)(ws + OFF_W0);
  bf16* A1  = (bf16*)(ws + OFF_A1);
  bf16* Wt1 = (bf16*)(ws + OFF_W1);
  bf16* A2  = (bf16*)(ws + OFF_A2);
  bf16* Wt2 = (bf16*)(ws + OFF_W2);
  bf16* A3  = (bf16*)(ws + OFF_A3);
  bf16* WtO = (bf16*)(ws + OFF_WO);

  // --- activation packing (bf16) ---
  {
    int t4 = BB * ISZ / 4;
    pack_bf16_k<<<(t4 + 255) / 256, 256, 0, stream>>>(x, A0, ISZ, ISZ + NN, 0, t4);
  }
  {
    int t4 = BB * NN / 4;
    pack_bf16_k<<<(t4 + 255) / 256, 256, 0, stream>>>(h0_in, A0, NN, ISZ + NN, ISZ, t4);
    pack_bf16_k<<<(t4 + 255) / 256, 256, 0, stream>>>(h1_in, A1, NN, 2 * NN, NN, t4);
    pack_bf16_k<<<(t4 + 255) / 256, 256, 0, stream>>>(h2_in, A2, NN, 2 * NN, NN, t4);
  }

  // --- weight transposes (-> N x K bf16, masks/diag fused) ---
  dim3 tb(32, 8);
  transpose_bf16_k<0><<<dim3(ISZ / 32, NN / 32), tb, 0, stream>>>(i_to_h0, nullptr, NN, Wt0, ISZ + NN, 0);
  transpose_bf16_k<1><<<dim3(NN / 32, NN / 32), tb, 0, stream>>>(h0_w, nullptr, NN, Wt0, ISZ + NN, ISZ);
  transpose_bf16_k<2><<<dim3(NN / 32, NN / 32), tb, 0, stream>>>(h0_to_h1, m01, NN, Wt1, 2 * NN, 0);
  transpose_bf16_k<1><<<dim3(NN / 32, NN / 32), tb, 0, stream>>>(h1_w, nullptr, NN, Wt1, 2 * NN, NN);
  transpose_bf16_k<2><<<dim3(NN / 32, NN / 32), tb, 0, stream>>>(h1_to_h2, m12, NN, Wt2, 2 * NN, 0);
  transpose_bf16_k<1><<<dim3(NN / 32, NN / 32), tb, 0, stream>>>(h2_w, nullptr, NN, Wt2, 2 * NN, NN);
  transpose_bf16_k<0><<<dim3(NN / 32, OSZ / 32), tb, 0, stream>>>(w_out, nullptr, OSZ, WtO, NN, 0);

  // --- layer GEMMs (output regions: h0, h1, h2, out) ---
  float* o_h0  = out;
  float* o_h1  = out + (size_t)BB * NN;
  float* o_h2  = out + (size_t)2 * BB * NN;
  float* o_out = out + (size_t)3 * BB * NN;

  gemm_bf16_k<128, 128, 0><<<dim3(NN / 128, BB / 128), 256, 0, stream>>>(
      A0, Wt0, ISZ + NN, ISZ + NN, ISZ + NN, h0_in, h0_b, o_h0, NN, A1, 2 * NN);
  gemm_bf16_k<128, 128, 0><<<dim3(NN / 128, BB / 128), 256, 0, stream>>>(
      A1, Wt1, 2 * NN, 2 * NN, 2 * NN, h1_in, h1_b, o_h1, NN, A2, 2 * NN);
  gemm_bf16_k<128, 128, 0><<<dim3(NN / 128, BB / 128), 256, 0, stream>>>(
      A2, Wt2, 2 * NN, 2 * NN, 2 * NN, h2_in, h2_b, o_h2, NN, A3, NN);
  gemm_bf16_k<32, 64, 1><<<dim3(OSZ / 64, BB / 32), 256, 0, stream>>>(
      A3, WtO, NN, NN, NN, nullptr, nullptr, o_out, OSZ, nullptr, 0);
}